// Round 7
// baseline (50390.579 us; speedup 1.0000x reference)
//
#include <hip/hip_runtime.h>

typedef _Float16 f16;
typedef _Float16 f16x8 __attribute__((ext_vector_type(8)));
typedef float f32x4 __attribute__((ext_vector_type(4)));

#define BS 64
#define SL 256
#define FL 256
#define SI 512
#define SH 512
#define NBLK 256
#define ESTEPS 1027

__device__ __forceinline__ float sigmoidf_(float x) { return 1.f / (1.f + __expf(-x)); }
__device__ __forceinline__ float tanhf_(float x) { float e = __expf(2.f * x); return 1.f - 2.f / (e + 1.f); }

// Weights packed in MFMA-fragment order:
// widx = (((((cell*32+nt)*4+g)*2+kh)*16+kk)*64 + lane)*8 + j
// n = g*512 + nt*16 + (lane&15), k = kh*512 + kk*32 + (lane>>4)*8 + j
__global__ void conv_w(const float* __restrict__ W, const float* __restrict__ V,
                       f16* __restrict__ out) {
  long idx = (long)blockIdx.x * blockDim.x + threadIdx.x;  // total 2^25
  int j    = (int)(idx & 7);
  int lane = (int)((idx >> 3) & 63);
  int kk   = (int)((idx >> 9) & 15);
  int kh   = (int)((idx >> 13) & 1);
  int g    = (int)((idx >> 14) & 3);
  int nt   = (int)((idx >> 16) & 31);
  long cell = idx >> 21;
  int n = g * 512 + nt * 16 + (lane & 15);
  int k = kh * 512 + kk * 32 + (lane >> 4) * 8 + j;
  float v = (k < 512) ? W[(cell * 512 + k) * 2048 + n]
                      : V[(cell * 512 + (k - 512)) * 2048 + n];
  out[idx] = (f16)v;
}

__global__ void conv_x(const float* __restrict__ x, f16* __restrict__ xt) {
  long idx = (long)blockIdx.x * blockDim.x + threadIdx.x;  // 256*64*512
  int i = (int)(idx & 511);
  int b = (int)((idx >> 9) & 63);
  int t = (int)(idx >> 15);
  xt[idx] = (f16)x[((long)b * SL + t) * SI + i];
}

__global__ void conv_fin(const float* __restrict__ finW, f16* __restrict__ fint) {
  long idx = (long)blockIdx.x * blockDim.x + threadIdx.x;  // 512*512
  int k = (int)(idx & 511);
  int n = (int)(idx >> 9);
  fint[idx] = (f16)finW[(long)k * SI + n];
}

// h_enc both parities = enc_h0 ; h_dec parity-1 slabs = dec_h0
__global__ void init_state(const float* __restrict__ h0e, const float* __restrict__ h0d,
                           f16* __restrict__ h_enc, f16* __restrict__ h_dec) {
  long idx = (long)blockIdx.x * blockDim.x + threadIdx.x;  // 4*64*512 = 131072
  f16 he = (f16)h0e[idx];
  h_enc[idx] = he;
  h_enc[idx + 131072] = he;
  h_dec[idx + 131072] = (f16)h0d[idx];
}

__device__ __forceinline__ void store_h_agent(f16* p, float v) {
  f16 h = (f16)v;
  __hip_atomic_store((unsigned short*)p, __builtin_bit_cast(unsigned short, h),
                     __ATOMIC_RELAXED, __HIP_MEMORY_SCOPE_AGENT);
}

// Raw block barrier for LDS visibility only: lgkmcnt drain, vmcnt stays in flight.
#define RAWBAR() do {                                                             \
    asm volatile("s_waitcnt lgkmcnt(0)" ::: "memory");                            \
    __builtin_amdgcn_sched_barrier(0);                                            \
    __builtin_amdgcn_s_barrier();                                                 \
    __builtin_amdgcn_sched_barrier(0);                                            \
  } while (0)

// Device-wide barrier, one-hop: per-block flag (stores already ordered per wave
// via vmcnt(16)); wave 0 polls all 256 flags; single acquire fence per block.
#define END_STEP(TARGET) do {                                                      \
    __builtin_amdgcn_s_barrier();                                                  \
    asm volatile("" ::: "memory");                                                 \
    if (tid == 0)                                                                  \
      __hip_atomic_store(&bar[bflag], (TARGET), __ATOMIC_RELAXED,                  \
                         __HIP_MEMORY_SCOPE_AGENT);                                \
    if (wid == 0) {                                                                \
      for (;;) {                                                                   \
        int a0 = __hip_atomic_load(&bar[pf0], __ATOMIC_RELAXED,                    \
                                   __HIP_MEMORY_SCOPE_AGENT);                      \
        int a1 = __hip_atomic_load(&bar[pf1], __ATOMIC_RELAXED,                    \
                                   __HIP_MEMORY_SCOPE_AGENT);                      \
        int a2 = __hip_atomic_load(&bar[pf2], __ATOMIC_RELAXED,                    \
                                   __HIP_MEMORY_SCOPE_AGENT);                      \
        int a3 = __hip_atomic_load(&bar[pf3], __ATOMIC_RELAXED,                    \
                                   __HIP_MEMORY_SCOPE_AGENT);                      \
        if (a0 >= (TARGET) && a1 >= (TARGET) && a2 >= (TARGET) && a3 >= (TARGET))  \
          break;                                                                   \
        __builtin_amdgcn_s_sleep(2);                                               \
      }                                                                            \
    }                                                                              \
    __builtin_amdgcn_s_barrier();                                                  \
    if (tid == 0) __builtin_amdgcn_fence(__ATOMIC_ACQUIRE, "agent");               \
    __builtin_amdgcn_s_barrier();                                                  \
    asm volatile("" ::: "memory");                                                 \
    __builtin_amdgcn_sched_barrier(0);                                             \
  } while (0)

// Per-wave ordered arrive: h/ys stores (older) retired by vmcnt(16); the 16
// prefetch loads (newer) stay in flight across the barrier.
#define WAVE_ORDER() do {                                                          \
    asm volatile("s_waitcnt vmcnt(16)" ::: "memory");                              \
    __builtin_amdgcn_sched_barrier(0);                                             \
  } while (0)

// Encoder body: anti-diagonal wavefront. 64 blocks per cell: (emt 0..1) x (nt 0..31).
#define ENC_BODY(DD, P, BUSE, BPRE, TARGET) do {                                   \
    const int v = (DD) - eslot;                                                    \
    if (v >= 0 && v < 1024) {                                                      \
      const int L = v & 3, t = v >> 2;                                             \
      const f16* inp = (eslot == 0) ? (xt + (long)t * HSz)                         \
                                    : (h_enc + ((P)*4 + (eslot - 1)) * HSz);       \
      const f16* hin = h_enc + ((P)*4 + eslot) * HSz;                              \
      f16* hout = h_enc + ((1 - (P))*4 + eslot) * HSz;                             \
      const f16* abase = ((kh == 0) ? inp : hin) + (emt*32 + col) * SH + kg * 8;   \
      f32x4 acc0 = 0.f, acc1 = 0.f;                                                \
      _Pragma("unroll")                                                            \
      for (int kk = 0; kk < 16; ++kk) {                                            \
        const f16* ab = abase + kk * 32;                                           \
        f16x8 a0 = *(const f16x8*)(ab);                                            \
        f16x8 a1 = *(const f16x8*)(ab + 16 * SH);                                  \
        acc0 = __builtin_amdgcn_mfma_f32_16x16x32_f16(a0, BUSE[kk], acc0, 0,0,0);  \
        acc1 = __builtin_amdgcn_mfma_f32_16x16x32_f16(a1, BUSE[kk], acc1, 0,0,0);  \
      }                                                                            \
      _Pragma("unroll")                                                            \
      for (int r = 0; r < 4; ++r) {                                                \
        zred[wid][kg*4 + r][col] = acc0[r];                                        \
        zred[wid][16 + kg*4 + r][col] = acc1[r];                                   \
      }                                                                            \
      RAWBAR();                                                                    \
      {                                                                            \
        const int row = tid >> 4, ci = tid & 15, n = n0 + ci;                      \
        const float* bl = bias_enc_lds + L * 64 + ci;                              \
        float zf = bl[0]  + zred[0][row][ci] + zred[4][row][ci];                   \
        float zi = bl[16] + zred[1][row][ci] + zred[5][row][ci];                   \
        float zg = bl[32] + zred[2][row][ci] + zred[6][row][ci];                   \
        float zo = bl[48] + zred[3][row][ci] + zred[7][row][ci];                   \
        float f_ = sigmoidf_(zf), i_ = sigmoidf_(zi);                              \
        float g_ = tanhf_(zg),   o_ = sigmoidf_(zo);                               \
        const int grow = emt * 32 + row;                                           \
        float cin = (v == 0) ? enc_c0[(long)eslot * HSz + grow * SH + n] : ce;     \
        float cc = f_ * cin + i_ * g_;                                             \
        ce = cc;                                                                   \
        store_h_agent(hout + grow * SH + n, o_ * tanhf_(cc));                      \
      }                                                                            \
      const f16* wn = (v + 1 < 1024)                                               \
          ? wt_enc + ((long)(((v + 1) & 3) * 4 + eslot) << 21) + wslice            \
          : wt_dec + wslice;                                                       \
      asm volatile("" ::: "memory");                                               \
      _Pragma("unroll")                                                            \
      for (int kk = 0; kk < 16; ++kk) BPRE[kk] = *(const f16x8*)(wn + kk * 512);   \
      WAVE_ORDER();                                                                \
    }                                                                              \
    END_STEP(TARGET);                                                              \
  } while (0)

// Decoder body: all 256 blocks on one cell: (dmt 0..7) x (nt 0..31).
#define DEC_BODY(E, BUSE, BPRE, CD, TARGET) do {                                   \
    const f16* inp;                                                                \
    if ((E) == 0)                                                                  \
      inp = (vv == 0) ? state0 : h_dec + ((par ^ 1) * 4 + 3) * HSz;                \
    else                                                                           \
      inp = h_dec + (par * 4 + (E) - 1) * HSz;                                     \
    const f16* hin = h_dec + ((par ^ 1) * 4 + (E)) * HSz;                          \
    f16* hout = h_dec + (par * 4 + (E)) * HSz;                                     \
    const f16* abase = ((kh == 0) ? inp : hin) + (dmt*8 + (col & 7)) * SH + kg*8;  \
    f32x4 acc = 0.f;                                                               \
    _Pragma("unroll")                                                              \
    for (int kk = 0; kk < 16; ++kk) {                                              \
      f16x8 a = *(const f16x8*)(abase + kk * 32);                                  \
      acc = __builtin_amdgcn_mfma_f32_16x16x32_f16(a, BUSE[kk], acc, 0,0,0);       \
    }                                                                              \
    if (kg < 2) {                                                                  \
      _Pragma("unroll")                                                            \
      for (int r = 0; r < 4; ++r) zred[wid][kg*4 + r][col] = acc[r];               \
    }                                                                              \
    RAWBAR();                                                                      \
    if (tid < 128) {                                                               \
      const int row = tid >> 4, ci = tid & 15, n = n0 + ci;                        \
      const float* bl = bias_dec_lds + (L * 4 + (E)) * 64 + ci;                    \
      float zf = bl[0]  + zred[0][row][ci] + zred[4][row][ci];                     \
      float zi = bl[16] + zred[1][row][ci] + zred[5][row][ci];                     \
      float zg = bl[32] + zred[2][row][ci] + zred[6][row][ci];                     \
      float zo = bl[48] + zred[3][row][ci] + zred[7][row][ci];                     \
      float f_ = sigmoidf_(zf), i_ = sigmoidf_(zi);                                \
      float g_ = tanhf_(zg),   o_ = sigmoidf_(zo);                                 \
      const int grow = dmt * 8 + row;                                              \
      float cin = (vv == 0) ? dec_c0[(long)(E) * HSz + grow * SH + n] : CD;        \
      float cc = f_ * cin + i_ * g_;                                               \
      CD = cc;                                                                     \
      float hv = o_ * tanhf_(cc);                                                  \
      store_h_agent(hout + grow * SH + n, hv);                                     \
      if ((E) == 3) ys[((long)grow * 1024 + vv) * SH + n] = (f16)hv;               \
    }                                                                              \
    {                                                                              \
      const int Lp = ((E) < 3) ? L : ((vv + 1) & 3);                               \
      const int Ep = ((E) + 1) & 3;                                                \
      const f16* wn = wt_dec + ((long)(Lp * 4 + Ep) << 21) + wslice;               \
      asm volatile("" ::: "memory");                                               \
      _Pragma("unroll")                                                            \
      for (int kk = 0; kk < 16; ++kk) BPRE[kk] = *(const f16x8*)(wn + kk * 512);   \
      WAVE_ORDER();                                                                \
    }                                                                              \
    END_STEP(TARGET);                                                              \
  } while (0)

__global__ __launch_bounds__(512, 2) void lstm_persist(
    const f16* __restrict__ xt,
    const f16* __restrict__ wt_enc, const f16* __restrict__ wt_dec,
    const float* __restrict__ enc_b, const float* __restrict__ dec_b,
    const float* __restrict__ enc_c0, const float* __restrict__ dec_c0,
    f16* __restrict__ h_enc, f16* __restrict__ h_dec,
    f16* __restrict__ ys, int* __restrict__ bar) {
  const int tid = threadIdx.x;
  const int lane = tid & 63;
  const int wid = tid >> 6;   // 0..7
  const int g = wid & 3;      // gate
  const int kh = wid >> 2;    // K-half
  const int col = lane & 15;
  const int kg = lane >> 4;
  const int idx = blockIdx.x;
  const int nt = idx & 31;        // idx%8 == nt%8 -> weight-sharing siblings co-XCD
  const int n0 = nt << 4;
  const int eslot = idx >> 6;     // encoder role: 4 groups of 64 blocks
  const int emt = (idx >> 5) & 1; // encoder M-split (32 rows)
  const int dmt = idx >> 5;       // decoder M-split (8 rows)

  const int bflag = idx * 16;
  const int pf0 = (lane * 4 + 0) * 16;
  const int pf1 = (lane * 4 + 1) * 16;
  const int pf2 = (lane * 4 + 2) * 16;
  const int pf3 = (lane * 4 + 3) * 16;

  __shared__ float zred[8][32][17];
  __shared__ float bias_enc_lds[4 * 4 * 16];    // [L][g][ci]
  __shared__ float bias_dec_lds[16 * 4 * 16];   // [L*4+E][g][ci]

  const long wslice = ((long)(nt * 4 + g) * 2 + kh) * 8192 + lane * 8;
  const int HSz = BS * SH;
  const f16* const state0 = h_enc + (1 * 4 + 3) * HSz;

  // stage biases into LDS once (gate phase then touches no global memory)
  for (int i = tid; i < 256; i += 512) {
    int L = i >> 6, gg = (i >> 4) & 3, ci = i & 15;
    bias_enc_lds[i] = enc_b[(L * 4 + eslot) * 2048 + gg * 512 + n0 + ci];
  }
  for (int i = tid; i < 1024; i += 512) {
    int cell = i >> 6, gg = (i >> 4) & 3, ci = i & 15;
    bias_dec_lds[i] = dec_b[cell * 2048 + gg * 512 + n0 + ci];
  }

  f16x8 B[16], Bn[16];
  {  // preload first encoder cell (L=0, e=eslot) into the parity-matching buffer
    const f16* w = wt_enc + ((long)eslot << 21) + wslice;
    if (eslot & 1) {
#pragma unroll
      for (int kk = 0; kk < 16; ++kk) Bn[kk] = *(const f16x8*)(w + kk * 512);
    } else {
#pragma unroll
      for (int kk = 0; kk < 16; ++kk) B[kk] = *(const f16x8*)(w + kk * 512);
    }
  }
  __syncthreads();  // biases staged

  float ce = 0.f;
  float cd0 = 0.f, cd1 = 0.f, cd2 = 0.f, cd3 = 0.f;

  // -------- encoder: anti-diagonal wavefront, diagonals 0..1026 --------
  for (int d = 0;; d += 2) {
    ENC_BODY(d, 0, B, Bn, d + 1);
    if (d == 1026) break;
    ENC_BODY(d + 1, 1, Bn, B, d + 2);
  }

  // normalize: decoder cell 0 weights into B for all blocks
  if (eslot & 1) {
#pragma unroll
    for (int kk = 0; kk < 16; ++kk) B[kk] = Bn[kk];
  }

  // -------- decoder: fully serial, 4096 cells, unrolled x4 --------
  for (int vv = 0; vv < 1024; ++vv) {
    const int L = vv & 3, par = vv & 1;
    DEC_BODY(0, B, Bn, cd0, ESTEPS + vv * 4 + 1);
    DEC_BODY(1, Bn, B, cd1, ESTEPS + vv * 4 + 2);
    DEC_BODY(2, B, Bn, cd2, ESTEPS + vv * 4 + 3);
    DEC_BODY(3, Bn, B, cd3, ESTEPS + vv * 4 + 4);
  }
}

// out[m][n] = sigmoid( ys[m][:] @ fint[n][:] + fin_b[n] )
__global__ __launch_bounds__(256) void final_gemm(const f16* __restrict__ ys,
                                                  const f16* __restrict__ fint,
                                                  const float* __restrict__ finb,
                                                  float* __restrict__ out) {
  const int lane = threadIdx.x & 63;
  const int w = threadIdx.x >> 6;
  const int col = lane & 15;
  const int kg = lane >> 4;
  const long m0 = (long)blockIdx.y * 64;
  const int n0 = (blockIdx.x * 4 + w) * 16;

  f32x4 acc[4];
#pragma unroll
  for (int mi = 0; mi < 4; ++mi) acc[mi] = 0.f;

#pragma unroll 2
  for (int kk = 0; kk < 16; ++kk) {
    f16x8 b = *(const f16x8*)(fint + (long)(n0 + col) * 512 + kk * 32 + kg * 8);
#pragma unroll
    for (int mi = 0; mi < 4; ++mi) {
      f16x8 a = *(const f16x8*)(ys + (m0 + mi * 16 + col) * 512 + kk * 32 + kg * 8);
      acc[mi] = __builtin_amdgcn_mfma_f32_16x16x32_f16(a, b, acc[mi], 0, 0, 0);
    }
  }
  const int n = n0 + col;
  const float bn = finb[n];
#pragma unroll
  for (int mi = 0; mi < 4; ++mi)
#pragma unroll
    for (int r = 0; r < 4; ++r)
      out[(m0 + mi * 16 + kg * 4 + r) * 512 + n] = sigmoidf_(acc[mi][r] + bn);
}

extern "C" void kernel_launch(void* const* d_in, const int* in_sizes, int n_in,
                              void* d_out, int out_size, void* d_ws, size_t ws_size,
                              hipStream_t stream) {
  const float* x      = (const float*)d_in[0];
  const float* enc_W  = (const float*)d_in[2];
  const float* enc_V  = (const float*)d_in[3];
  const float* enc_b  = (const float*)d_in[4];
  const float* enc_h0 = (const float*)d_in[5];
  const float* enc_c0 = (const float*)d_in[6];
  const float* dec_W  = (const float*)d_in[7];
  const float* dec_V  = (const float*)d_in[8];
  const float* dec_b  = (const float*)d_in[9];
  const float* dec_h0 = (const float*)d_in[10];
  const float* dec_c0 = (const float*)d_in[11];
  const float* fin_W  = (const float*)d_in[12];
  const float* fin_b  = (const float*)d_in[13];
  float* out = (float*)d_out;

  // workspace layout
  f16* wt_enc = (f16*)d_ws;                                   // 16*2048*1024
  f16* wt_dec = wt_enc + (long)16 * 2048 * 1024;              // 16*2048*1024
  f16* xt     = wt_dec + (long)16 * 2048 * 1024;              // 256*64*512
  f16* fint   = xt + (long)SL * BS * SI;                      // 512*512
  f16* ys     = fint + (long)SH * SI;                         // 64*1024*512
  f16* h_enc  = ys + (long)BS * (FL * 4) * SH;                // 2*4*64*512
  f16* h_dec  = h_enc + (long)2 * 4 * BS * SH;                // 2*4*64*512
  float* c_unused = (float*)(h_dec + (long)2 * 4 * BS * SH);  // reserved
  int* bar = (int*)(c_unused + (long)8 * BS * SH);            // 256 flags x 64B

  hipMemsetAsync(bar, 0, 32768, stream);

  conv_w<<<131072, 256, 0, stream>>>(enc_W, enc_V, wt_enc);
  conv_w<<<131072, 256, 0, stream>>>(dec_W, dec_V, wt_dec);
  conv_x<<<32768, 256, 0, stream>>>(x, xt);
  conv_fin<<<1024, 256, 0, stream>>>(fin_W, fint);
  init_state<<<512, 256, 0, stream>>>(enc_h0, dec_h0, h_enc, h_dec);

  lstm_persist<<<NBLK, 512, 0, stream>>>(xt, wt_enc, wt_dec, enc_b, dec_b,
                                         enc_c0, dec_c0, h_enc, h_dec, ys, bar);

  dim3 fg(8, 1024);
  final_gemm<<<fg, 256, 0, stream>>>(ys, fint, fin_b, out);
}

// Round 8
// 40097.723 us; speedup vs baseline: 1.2567x; 1.2567x over previous
//
#include <hip/hip_runtime.h>

typedef _Float16 f16;
typedef _Float16 f16x8 __attribute__((ext_vector_type(8)));
typedef float f32x4 __attribute__((ext_vector_type(4)));

#define BS 64
#define SL 256
#define FL 256
#define SI 512
#define SH 512
#define NBLK 256
#define ESTEPS 1027

__device__ __forceinline__ float sigmoidf_(float x) { return 1.f / (1.f + __expf(-x)); }
__device__ __forceinline__ float tanhf_(float x) { float e = __expf(2.f * x); return 1.f - 2.f / (e + 1.f); }

// Coherent 16B load: bypass L1+L2, read from the device coherence point (L3).
// Replaces the per-step acquire fence (buffer_inv) entirely.
__device__ __forceinline__ f16x8 ldg_cohere(const f16* p) {
  f16x8 r;
  asm volatile("global_load_dwordx4 %0, %1, off sc0 sc1"
               : "=v"(r) : "v"(p) : "memory");
  return r;
}

// Weights packed in MFMA-fragment order:
// widx = (((((cell*32+nt)*4+g)*2+kh)*16+kk)*64 + lane)*8 + j
// n = g*512 + nt*16 + (lane&15), k = kh*512 + kk*32 + (lane>>4)*8 + j
__global__ void conv_w(const float* __restrict__ W, const float* __restrict__ V,
                       f16* __restrict__ out) {
  long idx = (long)blockIdx.x * blockDim.x + threadIdx.x;  // total 2^25
  int j    = (int)(idx & 7);
  int lane = (int)((idx >> 3) & 63);
  int kk   = (int)((idx >> 9) & 15);
  int kh   = (int)((idx >> 13) & 1);
  int g    = (int)((idx >> 14) & 3);
  int nt   = (int)((idx >> 16) & 31);
  long cell = idx >> 21;
  int n = g * 512 + nt * 16 + (lane & 15);
  int k = kh * 512 + kk * 32 + (lane >> 4) * 8 + j;
  float v = (k < 512) ? W[(cell * 512 + k) * 2048 + n]
                      : V[(cell * 512 + (k - 512)) * 2048 + n];
  out[idx] = (f16)v;
}

__global__ void conv_x(const float* __restrict__ x, f16* __restrict__ xt) {
  long idx = (long)blockIdx.x * blockDim.x + threadIdx.x;  // 256*64*512
  int i = (int)(idx & 511);
  int b = (int)((idx >> 9) & 63);
  int t = (int)(idx >> 15);
  xt[idx] = (f16)x[((long)b * SL + t) * SI + i];
}

__global__ void conv_fin(const float* __restrict__ finW, f16* __restrict__ fint) {
  long idx = (long)blockIdx.x * blockDim.x + threadIdx.x;  // 512*512
  int k = (int)(idx & 511);
  int n = (int)(idx >> 9);
  fint[idx] = (f16)finW[(long)k * SI + n];
}

// h_enc both parities = enc_h0 ; h_dec parity-1 slabs = dec_h0
__global__ void init_state(const float* __restrict__ h0e, const float* __restrict__ h0d,
                           f16* __restrict__ h_enc, f16* __restrict__ h_dec) {
  long idx = (long)blockIdx.x * blockDim.x + threadIdx.x;  // 4*64*512 = 131072
  f16 he = (f16)h0e[idx];
  h_enc[idx] = he;
  h_enc[idx + 131072] = he;
  h_dec[idx + 131072] = (f16)h0d[idx];
}

__device__ __forceinline__ void store_h_agent(f16* p, float v) {
  f16 h = (f16)v;
  __hip_atomic_store((unsigned short*)p, __builtin_bit_cast(unsigned short, h),
                     __ATOMIC_RELAXED, __HIP_MEMORY_SCOPE_AGENT);
}

// Block barrier for LDS visibility only: lgkmcnt drain, vmcnt stays in flight.
#define RAWBAR() do {                                                             \
    asm volatile("s_waitcnt lgkmcnt(0)" ::: "memory");                            \
    __builtin_amdgcn_sched_barrier(0);                                            \
    __builtin_amdgcn_s_barrier();                                                 \
    __builtin_amdgcn_sched_barrier(0);                                            \
  } while (0)

// Ordered arrive: h/ys stores (older) acked at coherence point by vmcnt(16);
// the 16 weight-prefetch loads (newer) keep flying across the barrier.
#define WAVE_ORDER() do {                                                          \
    asm volatile("s_waitcnt vmcnt(16)" ::: "memory");                              \
    __builtin_amdgcn_sched_barrier(0);                                             \
  } while (0)

// Device-wide barrier, zero-fence: per-block flag store (already ordered after
// h-stores), wave 0 polls all 256 flags with relaxed agent loads. No buffer_inv.
#define END_STEP(TARGET) do {                                                      \
    __builtin_amdgcn_s_barrier();                                                  \
    asm volatile("" ::: "memory");                                                 \
    if (tid == 0)                                                                  \
      __hip_atomic_store(&bar[bflag], (TARGET), __ATOMIC_RELAXED,                  \
                         __HIP_MEMORY_SCOPE_AGENT);                                \
    if (wid == 0) {                                                                \
      for (;;) {                                                                   \
        int a0 = __hip_atomic_load(&bar[pf0], __ATOMIC_RELAXED,                    \
                                   __HIP_MEMORY_SCOPE_AGENT);                      \
        int a1 = __hip_atomic_load(&bar[pf1], __ATOMIC_RELAXED,                    \
                                   __HIP_MEMORY_SCOPE_AGENT);                      \
        int a2 = __hip_atomic_load(&bar[pf2], __ATOMIC_RELAXED,                    \
                                   __HIP_MEMORY_SCOPE_AGENT);                      \
        int a3 = __hip_atomic_load(&bar[pf3], __ATOMIC_RELAXED,                    \
                                   __HIP_MEMORY_SCOPE_AGENT);                      \
        if (a0 >= (TARGET) && a1 >= (TARGET) && a2 >= (TARGET) && a3 >= (TARGET))  \
          break;                                                                   \
        __builtin_amdgcn_s_sleep(2);                                               \
      }                                                                            \
    }                                                                              \
    __builtin_amdgcn_s_barrier();                                                  \
    asm volatile("" ::: "memory");                                                 \
    __builtin_amdgcn_sched_barrier(0);                                             \
  } while (0)

// Encoder body: anti-diagonal wavefront. 64 blocks per cell: (emt 0..1) x (nt 0..31).
#define ENC_BODY(DD, P, TARGET) do {                                               \
    const int v = (DD) - eslot;                                                    \
    if (v >= 0 && v < 1024) {                                                      \
      const int L = v & 3, t = v >> 2;                                             \
      const f16* inp = (eslot == 0) ? (xt + (long)t * HSz)                         \
                                    : (h_enc + ((P)*4 + (eslot - 1)) * HSz);       \
      const f16* hin = h_enc + ((P)*4 + eslot) * HSz;                              \
      f16* hout = h_enc + ((1 - (P))*4 + eslot) * HSz;                             \
      const f16* abase = ((kh == 0) ? inp : hin) + (emt*32 + col) * SH + kg * 8;   \
      const f16* abase1 = abase + 16 * SH;                                         \
      f16x8 a0[16], a1[16];                                                        \
      _Pragma("unroll")                                                            \
      for (int kk = 0; kk < 16; ++kk) {                                            \
        a0[kk] = ldg_cohere(abase + kk * 32);                                      \
        a1[kk] = ldg_cohere(abase1 + kk * 32);                                     \
      }                                                                            \
      asm volatile("s_waitcnt vmcnt(0)" ::: "memory");                             \
      __builtin_amdgcn_sched_barrier(0);                                           \
      f32x4 acc0 = 0.f, acc1 = 0.f;                                                \
      _Pragma("unroll")                                                            \
      for (int kk = 0; kk < 16; ++kk) {                                            \
        acc0 = __builtin_amdgcn_mfma_f32_16x16x32_f16(a0[kk], B[kk], acc0, 0,0,0); \
        acc1 = __builtin_amdgcn_mfma_f32_16x16x32_f16(a1[kk], B[kk], acc1, 0,0,0); \
      }                                                                            \
      _Pragma("unroll")                                                            \
      for (int r = 0; r < 4; ++r) {                                                \
        zred[wid][kg*4 + r][col] = acc0[r];                                        \
        zred[wid][16 + kg*4 + r][col] = acc1[r];                                   \
      }                                                                            \
      RAWBAR();                                                                    \
      {                                                                            \
        const int row = tid >> 4, ci = tid & 15, n = n0 + ci;                      \
        const float* bl = bias_enc_lds + L * 64 + ci;                              \
        float zf = bl[0]  + zred[0][row][ci] + zred[4][row][ci];                   \
        float zi = bl[16] + zred[1][row][ci] + zred[5][row][ci];                   \
        float zg = bl[32] + zred[2][row][ci] + zred[6][row][ci];                   \
        float zo = bl[48] + zred[3][row][ci] + zred[7][row][ci];                   \
        float f_ = sigmoidf_(zf), i_ = sigmoidf_(zi);                              \
        float g_ = tanhf_(zg),   o_ = sigmoidf_(zo);                               \
        const int grow = emt * 32 + row;                                           \
        float cin = (v == 0) ? enc_c0[(long)eslot * HSz + grow * SH + n] : ce;     \
        float cc = f_ * cin + i_ * g_;                                             \
        ce = cc;                                                                   \
        store_h_agent(hout + grow * SH + n, o_ * tanhf_(cc));                      \
      }                                                                            \
      const f16* wn = (v + 1 < 1024)                                               \
          ? wt_enc + ((long)(((v + 1) & 3) * 4 + eslot) << 21) + wslice            \
          : wt_dec + wslice;                                                       \
      asm volatile("" ::: "memory");                                               \
      _Pragma("unroll")                                                            \
      for (int kk = 0; kk < 16; ++kk) B[kk] = *(const f16x8*)(wn + kk * 512);      \
      WAVE_ORDER();                                                                \
    }                                                                              \
    END_STEP(TARGET);                                                              \
  } while (0)

// Decoder body: all 256 blocks on one cell: (dmt 0..7) x (nt 0..31).
#define DEC_BODY(E, CD, TARGET) do {                                               \
    const f16* inp;                                                                \
    if ((E) == 0)                                                                  \
      inp = (vv == 0) ? state0 : h_dec + ((par ^ 1) * 4 + 3) * HSz;                \
    else                                                                           \
      inp = h_dec + (par * 4 + (E) - 1) * HSz;                                     \
    const f16* hin = h_dec + ((par ^ 1) * 4 + (E)) * HSz;                          \
    f16* hout = h_dec + (par * 4 + (E)) * HSz;                                     \
    const f16* abase = ((kh == 0) ? inp : hin) + (dmt*8 + (col & 7)) * SH + kg*8;  \
    f16x8 a[16];                                                                   \
    _Pragma("unroll")                                                              \
    for (int kk = 0; kk < 16; ++kk) a[kk] = ldg_cohere(abase + kk * 32);           \
    asm volatile("s_waitcnt vmcnt(0)" ::: "memory");                               \
    __builtin_amdgcn_sched_barrier(0);                                             \
    f32x4 acc = 0.f;                                                               \
    _Pragma("unroll")                                                              \
    for (int kk = 0; kk < 16; ++kk)                                                \
      acc = __builtin_amdgcn_mfma_f32_16x16x32_f16(a[kk], B[kk], acc, 0,0,0);      \
    if (kg < 2) {                                                                  \
      _Pragma("unroll")                                                            \
      for (int r = 0; r < 4; ++r) zred[wid][kg*4 + r][col] = acc[r];               \
    }                                                                              \
    RAWBAR();                                                                      \
    if (tid < 128) {                                                               \
      const int row = tid >> 4, ci = tid & 15, n = n0 + ci;                        \
      const float* bl = bias_dec_lds + (L * 4 + (E)) * 64 + ci;                    \
      float zf = bl[0]  + zred[0][row][ci] + zred[4][row][ci];                     \
      float zi = bl[16] + zred[1][row][ci] + zred[5][row][ci];                     \
      float zg = bl[32] + zred[2][row][ci] + zred[6][row][ci];                     \
      float zo = bl[48] + zred[3][row][ci] + zred[7][row][ci];                     \
      float f_ = sigmoidf_(zf), i_ = sigmoidf_(zi);                                \
      float g_ = tanhf_(zg),   o_ = sigmoidf_(zo);                                 \
      const int grow = dmt * 8 + row;                                              \
      float cin = (vv == 0) ? dec_c0[(long)(E) * HSz + grow * SH + n] : CD;        \
      float cc = f_ * cin + i_ * g_;                                               \
      CD = cc;                                                                     \
      float hv = o_ * tanhf_(cc);                                                  \
      store_h_agent(hout + grow * SH + n, hv);                                     \
      if ((E) == 3) ys[((long)grow * 1024 + vv) * SH + n] = (f16)hv;               \
    }                                                                              \
    {                                                                              \
      const int Lp = ((E) < 3) ? L : ((vv + 1) & 3);                               \
      const int Ep = ((E) + 1) & 3;                                                \
      const f16* wn = wt_dec + ((long)(Lp * 4 + Ep) << 21) + wslice;               \
      asm volatile("" ::: "memory");                                               \
      _Pragma("unroll")                                                            \
      for (int kk = 0; kk < 16; ++kk) B[kk] = *(const f16x8*)(wn + kk * 512);      \
      WAVE_ORDER();                                                                \
    }                                                                              \
    END_STEP(TARGET);                                                              \
  } while (0)

__global__ __launch_bounds__(512, 2) void lstm_persist(
    const f16* __restrict__ xt,
    const f16* __restrict__ wt_enc, const f16* __restrict__ wt_dec,
    const float* __restrict__ enc_b, const float* __restrict__ dec_b,
    const float* __restrict__ enc_c0, const float* __restrict__ dec_c0,
    f16* __restrict__ h_enc, f16* __restrict__ h_dec,
    f16* __restrict__ ys, int* __restrict__ bar) {
  const int tid = threadIdx.x;
  const int lane = tid & 63;
  const int wid = tid >> 6;   // 0..7
  const int g = wid & 3;      // gate
  const int kh = wid >> 2;    // K-half
  const int col = lane & 15;
  const int kg = lane >> 4;
  const int idx = blockIdx.x;
  const int nt = idx & 31;        // idx%8 == nt%8 -> weight-sharing siblings co-XCD
  const int n0 = nt << 4;
  const int eslot = idx >> 6;     // encoder role: 4 groups of 64 blocks
  const int emt = (idx >> 5) & 1; // encoder M-split (32 rows)
  const int dmt = idx >> 5;       // decoder M-split (8 rows)

  const int bflag = idx * 32;     // 128B stride: no line sharing
  const int pf0 = (lane * 4 + 0) * 32;
  const int pf1 = (lane * 4 + 1) * 32;
  const int pf2 = (lane * 4 + 2) * 32;
  const int pf3 = (lane * 4 + 3) * 32;

  __shared__ float zred[8][32][17];
  __shared__ float bias_enc_lds[4 * 4 * 16];    // [L][g][ci]
  __shared__ float bias_dec_lds[16 * 4 * 16];   // [L*4+E][g][ci]

  const long wslice = ((long)(nt * 4 + g) * 2 + kh) * 8192 + lane * 8;
  const int HSz = BS * SH;
  const f16* const state0 = h_enc + (1 * 4 + 3) * HSz;

  // stage biases into LDS once
  for (int i = tid; i < 256; i += 512) {
    int L = i >> 6, gg = (i >> 4) & 3, ci = i & 15;
    bias_enc_lds[i] = enc_b[(L * 4 + eslot) * 2048 + gg * 512 + n0 + ci];
  }
  for (int i = tid; i < 1024; i += 512) {
    int cell = i >> 6, gg = (i >> 4) & 3, ci = i & 15;
    bias_dec_lds[i] = dec_b[cell * 2048 + gg * 512 + n0 + ci];
  }

  f16x8 B[16];
  {  // preload first encoder cell (L=0, e=eslot)
    const f16* w = wt_enc + ((long)eslot << 21) + wslice;
#pragma unroll
    for (int kk = 0; kk < 16; ++kk) B[kk] = *(const f16x8*)(w + kk * 512);
  }
  __syncthreads();  // biases staged

  float ce = 0.f;
  float cd0 = 0.f, cd1 = 0.f, cd2 = 0.f, cd3 = 0.f;

  // -------- encoder: anti-diagonal wavefront, diagonals 0..1026 --------
  for (int d = 0;; d += 2) {
    ENC_BODY(d, 0, d + 1);
    if (d == 1026) break;
    ENC_BODY(d + 1, 1, d + 2);
  }

  // -------- decoder: fully serial, 4096 cells, unrolled x4 --------
  for (int vv = 0; vv < 1024; ++vv) {
    const int L = vv & 3, par = vv & 1;
    DEC_BODY(0, cd0, ESTEPS + vv * 4 + 1);
    DEC_BODY(1, cd1, ESTEPS + vv * 4 + 2);
    DEC_BODY(2, cd2, ESTEPS + vv * 4 + 3);
    DEC_BODY(3, cd3, ESTEPS + vv * 4 + 4);
  }
}

// out[m][n] = sigmoid( ys[m][:] @ fint[n][:] + fin_b[n] )
__global__ __launch_bounds__(256) void final_gemm(const f16* __restrict__ ys,
                                                  const f16* __restrict__ fint,
                                                  const float* __restrict__ finb,
                                                  float* __restrict__ out) {
  const int lane = threadIdx.x & 63;
  const int w = threadIdx.x >> 6;
  const int col = lane & 15;
  const int kg = lane >> 4;
  const long m0 = (long)blockIdx.y * 64;
  const int n0 = (blockIdx.x * 4 + w) * 16;

  f32x4 acc[4];
#pragma unroll
  for (int mi = 0; mi < 4; ++mi) acc[mi] = 0.f;

#pragma unroll 2
  for (int kk = 0; kk < 16; ++kk) {
    f16x8 b = *(const f16x8*)(fint + (long)(n0 + col) * 512 + kk * 32 + kg * 8);
#pragma unroll
    for (int mi = 0; mi < 4; ++mi) {
      f16x8 a = *(const f16x8*)(ys + (m0 + mi * 16 + col) * 512 + kk * 32 + kg * 8);
      acc[mi] = __builtin_amdgcn_mfma_f32_16x16x32_f16(a, b, acc[mi], 0, 0, 0);
    }
  }
  const int n = n0 + col;
  const float bn = finb[n];
#pragma unroll
  for (int mi = 0; mi < 4; ++mi)
#pragma unroll
    for (int r = 0; r < 4; ++r)
      out[(m0 + mi * 16 + kg * 4 + r) * 512 + n] = sigmoidf_(acc[mi][r] + bn);
}

extern "C" void kernel_launch(void* const* d_in, const int* in_sizes, int n_in,
                              void* d_out, int out_size, void* d_ws, size_t ws_size,
                              hipStream_t stream) {
  const float* x      = (const float*)d_in[0];
  const float* enc_W  = (const float*)d_in[2];
  const float* enc_V  = (const float*)d_in[3];
  const float* enc_b  = (const float*)d_in[4];
  const float* enc_h0 = (const float*)d_in[5];
  const float* enc_c0 = (const float*)d_in[6];
  const float* dec_W  = (const float*)d_in[7];
  const float* dec_V  = (const float*)d_in[8];
  const float* dec_b  = (const float*)d_in[9];
  const float* dec_h0 = (const float*)d_in[10];
  const float* dec_c0 = (const float*)d_in[11];
  const float* fin_W  = (const float*)d_in[12];
  const float* fin_b  = (const float*)d_in[13];
  float* out = (float*)d_out;

  // workspace layout
  f16* wt_enc = (f16*)d_ws;                                   // 16*2048*1024
  f16* wt_dec = wt_enc + (long)16 * 2048 * 1024;              // 16*2048*1024
  f16* xt     = wt_dec + (long)16 * 2048 * 1024;              // 256*64*512
  f16* fint   = xt + (long)SL * BS * SI;                      // 512*512
  f16* ys     = fint + (long)SH * SI;                         // 64*1024*512
  f16* h_enc  = ys + (long)BS * (FL * 4) * SH;                // 2*4*64*512
  f16* h_dec  = h_enc + (long)2 * 4 * BS * SH;                // 2*4*64*512
  float* c_unused = (float*)(h_dec + (long)2 * 4 * BS * SH);  // reserved
  int* bar = (int*)(c_unused + (long)8 * BS * SH);            // 256 flags x 128B

  hipMemsetAsync(bar, 0, 65536, stream);

  conv_w<<<131072, 256, 0, stream>>>(enc_W, enc_V, wt_enc);
  conv_w<<<131072, 256, 0, stream>>>(dec_W, dec_V, wt_dec);
  conv_x<<<32768, 256, 0, stream>>>(x, xt);
  conv_fin<<<1024, 256, 0, stream>>>(fin_W, fint);
  init_state<<<512, 256, 0, stream>>>(enc_h0, dec_h0, h_enc, h_dec);

  lstm_persist<<<NBLK, 512, 0, stream>>>(xt, wt_enc, wt_dec, enc_b, dec_b,
                                         enc_c0, dec_c0, h_enc, h_dec, ys, bar);

  dim3 fg(8, 1024);
  final_gemm<<<fg, 256, 0, stream>>>(ys, fint, fin_b, out);
}

// Round 9
// 24706.177 us; speedup vs baseline: 2.0396x; 1.6230x over previous
//
#include <hip/hip_runtime.h>

typedef _Float16 f16;
typedef _Float16 f16x8 __attribute__((ext_vector_type(8)));
typedef float f32x4 __attribute__((ext_vector_type(4)));

#define BS 64
#define SL 256
#define FL 256
#define SI 512
#define SH 512
#define NBLK 256
#define ESTEPS 1027

__device__ __forceinline__ float sigmoidf_(float x) { return 1.f / (1.f + __expf(-x)); }
__device__ __forceinline__ float tanhf_(float x) { float e = __expf(2.f * x); return 1.f - 2.f / (e + 1.f); }

// Coherent 16B load: bypass L1+L2, read from the device coherence point (L3).
__device__ __forceinline__ f16x8 ldg_cohere(const f16* p) {
  f16x8 r;
  asm volatile("global_load_dwordx4 %0, %1, off sc0 sc1"
               : "=v"(r) : "v"(p) : "memory");
  return r;
}

// Weights packed in MFMA-fragment order:
// widx = (((((cell*32+nt)*4+g)*2+kh)*16+kk)*64 + lane)*8 + j
// n = g*512 + nt*16 + (lane&15), k = kh*512 + kk*32 + (lane>>4)*8 + j
__global__ void conv_w(const float* __restrict__ W, const float* __restrict__ V,
                       f16* __restrict__ out) {
  long idx = (long)blockIdx.x * blockDim.x + threadIdx.x;  // total 2^25
  int j    = (int)(idx & 7);
  int lane = (int)((idx >> 3) & 63);
  int kk   = (int)((idx >> 9) & 15);
  int kh   = (int)((idx >> 13) & 1);
  int g    = (int)((idx >> 14) & 3);
  int nt   = (int)((idx >> 16) & 31);
  long cell = idx >> 21;
  int n = g * 512 + nt * 16 + (lane & 15);
  int k = kh * 512 + kk * 32 + (lane >> 4) * 8 + j;
  float v = (k < 512) ? W[(cell * 512 + k) * 2048 + n]
                      : V[(cell * 512 + (k - 512)) * 2048 + n];
  out[idx] = (f16)v;
}

__global__ void conv_x(const float* __restrict__ x, f16* __restrict__ xt) {
  long idx = (long)blockIdx.x * blockDim.x + threadIdx.x;  // 256*64*512
  int i = (int)(idx & 511);
  int b = (int)((idx >> 9) & 63);
  int t = (int)(idx >> 15);
  xt[idx] = (f16)x[((long)b * SL + t) * SI + i];
}

__global__ void conv_fin(const float* __restrict__ finW, f16* __restrict__ fint) {
  long idx = (long)blockIdx.x * blockDim.x + threadIdx.x;  // 512*512
  int k = (int)(idx & 511);
  int n = (int)(idx >> 9);
  fint[idx] = (f16)finW[(long)k * SI + n];
}

// h_enc both parities = enc_h0 ; h_dec parity-1 slabs = dec_h0
__global__ void init_state(const float* __restrict__ h0e, const float* __restrict__ h0d,
                           f16* __restrict__ h_enc, f16* __restrict__ h_dec) {
  long idx = (long)blockIdx.x * blockDim.x + threadIdx.x;  // 4*64*512 = 131072
  f16 he = (f16)h0e[idx];
  h_enc[idx] = he;
  h_enc[idx + 131072] = he;
  h_dec[idx + 131072] = (f16)h0d[idx];
}

__device__ __forceinline__ void store_h_agent(f16* p, float v) {
  f16 h = (f16)v;
  __hip_atomic_store((unsigned short*)p, __builtin_bit_cast(unsigned short, h),
                     __ATOMIC_RELAXED, __HIP_MEMORY_SCOPE_AGENT);
}

#define VMCNT0() do {                                                             \
    asm volatile("s_waitcnt vmcnt(0)" ::: "memory");                              \
    __builtin_amdgcn_sched_barrier(0);                                            \
  } while (0)

// Block barrier for LDS visibility only: lgkmcnt drain, vmcnt stays in flight.
#define RAWBAR() do {                                                             \
    asm volatile("s_waitcnt lgkmcnt(0)" ::: "memory");                            \
    __builtin_amdgcn_sched_barrier(0);                                            \
    __builtin_amdgcn_s_barrier();                                                 \
    __builtin_amdgcn_sched_barrier(0);                                            \
  } while (0)

// Ordered arrive: h/ys stores (older) acked at coherence point by vmcnt(16);
// the 16 weight-prefetch loads (newer) keep flying across the barrier.
#define WAVE_ORDER() do {                                                          \
    asm volatile("s_waitcnt vmcnt(16)" ::: "memory");                              \
    __builtin_amdgcn_sched_barrier(0);                                             \
  } while (0)

// Device-wide barrier, zero-fence (R8 protocol, unchanged).
#define END_STEP(TARGET) do {                                                      \
    __builtin_amdgcn_s_barrier();                                                  \
    asm volatile("" ::: "memory");                                                 \
    if (tid == 0)                                                                  \
      __hip_atomic_store(&bar[bflag], (TARGET), __ATOMIC_RELAXED,                  \
                         __HIP_MEMORY_SCOPE_AGENT);                                \
    if (wid == 0) {                                                                \
      for (;;) {                                                                   \
        int a0 = __hip_atomic_load(&bar[pf0], __ATOMIC_RELAXED,                    \
                                   __HIP_MEMORY_SCOPE_AGENT);                      \
        int a1 = __hip_atomic_load(&bar[pf1], __ATOMIC_RELAXED,                    \
                                   __HIP_MEMORY_SCOPE_AGENT);                      \
        int a2 = __hip_atomic_load(&bar[pf2], __ATOMIC_RELAXED,                    \
                                   __HIP_MEMORY_SCOPE_AGENT);                      \
        int a3 = __hip_atomic_load(&bar[pf3], __ATOMIC_RELAXED,                    \
                                   __HIP_MEMORY_SCOPE_AGENT);                      \
        if (a0 >= (TARGET) && a1 >= (TARGET) && a2 >= (TARGET) && a3 >= (TARGET))  \
          break;                                                                   \
        __builtin_amdgcn_s_sleep(2);                                               \
      }                                                                            \
    }                                                                              \
    __builtin_amdgcn_s_barrier();                                                  \
    asm volatile("" ::: "memory");                                                 \
    __builtin_amdgcn_sched_barrier(0);                                             \
  } while (0)

// Encoder body. A staged through LDS once per block (was 4x-duplicated L3 reads).
#define ENC_BODY(DD, P, TARGET) do {                                               \
    const int v = (DD) - eslot;                                                    \
    if (v >= 0 && v < 1024) {                                                      \
      const int L = v & 3, t = v >> 2;                                             \
      const f16* inp = (eslot == 0) ? (xt + (long)t * HSz)                         \
                                    : (h_enc + ((P)*4 + (eslot - 1)) * HSz);       \
      const f16* hin = h_enc + ((P)*4 + eslot) * HSz;                              \
      f16* hout = h_enc + ((1 - (P))*4 + eslot) * HSz;                             \
      { /* stage inp chunk then hin chunk (two 4-load reg batches) */              \
        const f16* sA = inp + emt * 16384 + tid * 32;                              \
        f16x8 t0 = ldg_cohere(sA + 0),  t1 = ldg_cohere(sA + 8);                   \
        f16x8 t2 = ldg_cohere(sA + 16), t3 = ldg_cohere(sA + 24);                  \
        VMCNT0();                                                                  \
        f16* d = &As[0][tid >> 4][(tid & 15) * 32];                                \
        *(f16x8*)(d) = t0; *(f16x8*)(d + 8) = t1;                                  \
        *(f16x8*)(d + 16) = t2; *(f16x8*)(d + 24) = t3;                            \
        const f16* sB = hin + emt * 16384 + tid * 32;                              \
        t0 = ldg_cohere(sB + 0);  t1 = ldg_cohere(sB + 8);                         \
        t2 = ldg_cohere(sB + 16); t3 = ldg_cohere(sB + 24);                        \
        VMCNT0();                                                                  \
        f16* d2 = &As[1][tid >> 4][(tid & 15) * 32];                               \
        *(f16x8*)(d2) = t0; *(f16x8*)(d2 + 8) = t1;                                \
        *(f16x8*)(d2 + 16) = t2; *(f16x8*)(d2 + 24) = t3;                          \
      }                                                                            \
      RAWBAR();                                                                    \
      f32x4 acc0 = 0.f, acc1 = 0.f;                                                \
      _Pragma("unroll")                                                            \
      for (int kk = 0; kk < 16; ++kk) {                                            \
        f16x8 a0 = *(const f16x8*)&As[kh][col][kk * 32 + kg * 8];                  \
        f16x8 a1 = *(const f16x8*)&As[kh][16 + col][kk * 32 + kg * 8];             \
        acc0 = __builtin_amdgcn_mfma_f32_16x16x32_f16(a0, B[kk], acc0, 0,0,0);     \
        acc1 = __builtin_amdgcn_mfma_f32_16x16x32_f16(a1, B[kk], acc1, 0,0,0);     \
      }                                                                            \
      RAWBAR(); /* all stage reads done; zred (unioned) may now overwrite */       \
      _Pragma("unroll")                                                            \
      for (int r = 0; r < 4; ++r) {                                                \
        zred[wid][kg*4 + r][col] = acc0[r];                                        \
        zred[wid][16 + kg*4 + r][col] = acc1[r];                                   \
      }                                                                            \
      RAWBAR();                                                                    \
      {                                                                            \
        const int row = tid >> 4, ci = tid & 15, n = n0 + ci;                      \
        const float* bl = bias_enc_lds + L * 64 + ci;                              \
        float zf = bl[0]  + zred[0][row][ci] + zred[4][row][ci];                   \
        float zi = bl[16] + zred[1][row][ci] + zred[5][row][ci];                   \
        float zg = bl[32] + zred[2][row][ci] + zred[6][row][ci];                   \
        float zo = bl[48] + zred[3][row][ci] + zred[7][row][ci];                   \
        float f_ = sigmoidf_(zf), i_ = sigmoidf_(zi);                              \
        float g_ = tanhf_(zg),   o_ = sigmoidf_(zo);                               \
        const int grow = emt * 32 + row;                                           \
        float cin = (v == 0) ? enc_c0[(long)eslot * HSz + grow * SH + n] : ce;     \
        float cc = f_ * cin + i_ * g_;                                             \
        ce = cc;                                                                   \
        store_h_agent(hout + grow * SH + n, o_ * tanhf_(cc));                      \
      }                                                                            \
      const f16* wn = (v + 1 < 1024)                                               \
          ? wt_enc + ((long)(((v + 1) & 3) * 4 + eslot) << 21) + wslice            \
          : wt_dec + wslice;                                                       \
      asm volatile("" ::: "memory");                                               \
      _Pragma("unroll")                                                            \
      for (int kk = 0; kk < 16; ++kk) B[kk] = *(const f16x8*)(wn + kk * 512);      \
      WAVE_ORDER();                                                                \
    }                                                                              \
    END_STEP(TARGET);                                                              \
  } while (0)

// Decoder body. Stage unique 16KB (inp+hin 8 rows each) once per block.
#define DEC_BODY(E, CD, TARGET) do {                                               \
    const f16* inp;                                                                \
    if ((E) == 0)                                                                  \
      inp = (vv == 0) ? state0 : h_dec + ((par ^ 1) * 4 + 3) * HSz;                \
    else                                                                           \
      inp = h_dec + (par * 4 + (E) - 1) * HSz;                                     \
    const f16* hin = h_dec + ((par ^ 1) * 4 + (E)) * HSz;                          \
    f16* hout = h_dec + (par * 4 + (E)) * HSz;                                     \
    {                                                                              \
      const int idx16 = tid * 16;                                                  \
      const int ch = idx16 >> 12;                                                  \
      const int off = idx16 & 4095;                                                \
      const f16* src = (ch ? hin : inp) + dmt * 4096 + off;                        \
      f16x8 t0 = ldg_cohere(src), t1 = ldg_cohere(src + 8);                        \
      VMCNT0();                                                                    \
      f16* d = &As[ch][off >> 9][off & 511];                                       \
      *(f16x8*)(d) = t0; *(f16x8*)(d + 8) = t1;                                    \
    }                                                                              \
    RAWBAR();                                                                      \
    f32x4 acc = 0.f;                                                               \
    _Pragma("unroll")                                                              \
    for (int kk = 0; kk < 16; ++kk) {                                              \
      f16x8 a = *(const f16x8*)&As[kh][col & 7][kk * 32 + kg * 8];                 \
      acc = __builtin_amdgcn_mfma_f32_16x16x32_f16(a, B[kk], acc, 0,0,0);          \
    }                                                                              \
    RAWBAR(); /* stage reads done; zred (unioned) may now overwrite */             \
    if (kg < 2) {                                                                  \
      _Pragma("unroll")                                                            \
      for (int r = 0; r < 4; ++r) zred[wid][kg*4 + r][col] = acc[r];               \
    }                                                                              \
    RAWBAR();                                                                      \
    if (tid < 128) {                                                               \
      const int row = tid >> 4, ci = tid & 15, n = n0 + ci;                        \
      const float* bl = bias_dec_lds + (L * 4 + (E)) * 64 + ci;                    \
      float zf = bl[0]  + zred[0][row][ci] + zred[4][row][ci];                     \
      float zi = bl[16] + zred[1][row][ci] + zred[5][row][ci];                     \
      float zg = bl[32] + zred[2][row][ci] + zred[6][row][ci];                     \
      float zo = bl[48] + zred[3][row][ci] + zred[7][row][ci];                     \
      float f_ = sigmoidf_(zf), i_ = sigmoidf_(zi);                                \
      float g_ = tanhf_(zg),   o_ = sigmoidf_(zo);                                 \
      const int grow = dmt * 8 + row;                                              \
      float cin = (vv == 0) ? dec_c0[(long)(E) * HSz + grow * SH + n] : CD;        \
      float cc = f_ * cin + i_ * g_;                                               \
      CD = cc;                                                                     \
      float hv = o_ * tanhf_(cc);                                                  \
      store_h_agent(hout + grow * SH + n, hv);                                     \
      if ((E) == 3) ys[((long)grow * 1024 + vv) * SH + n] = (f16)hv;               \
    }                                                                              \
    {                                                                              \
      const int Lp = ((E) < 3) ? L : ((vv + 1) & 3);                               \
      const int Ep = ((E) + 1) & 3;                                                \
      const f16* wn = wt_dec + ((long)(Lp * 4 + Ep) << 21) + wslice;               \
      asm volatile("" ::: "memory");                                               \
      _Pragma("unroll")                                                            \
      for (int kk = 0; kk < 16; ++kk) B[kk] = *(const f16x8*)(wn + kk * 512);      \
      WAVE_ORDER();                                                                \
    }                                                                              \
    END_STEP(TARGET);                                                              \
  } while (0)

__global__ __launch_bounds__(512, 2) void lstm_persist(
    const f16* __restrict__ xt,
    const f16* __restrict__ wt_enc, const f16* __restrict__ wt_dec,
    const float* __restrict__ enc_b, const float* __restrict__ dec_b,
    const float* __restrict__ enc_c0, const float* __restrict__ dec_c0,
    f16* __restrict__ h_enc, f16* __restrict__ h_dec,
    f16* __restrict__ ys, int* __restrict__ bar) {
  const int tid = threadIdx.x;
  const int lane = tid & 63;
  const int wid = tid >> 6;   // 0..7
  const int g = wid & 3;      // gate
  const int kh = wid >> 2;    // K-half
  const int col = lane & 15;
  const int kg = lane >> 4;
  const int idx = blockIdx.x;
  const int nt = idx & 31;        // idx%8 == nt%8 -> weight-sharing siblings co-XCD
  const int n0 = nt << 4;
  const int eslot = idx >> 6;     // encoder role: 4 groups of 64 blocks
  const int emt = (idx >> 5) & 1; // encoder M-split (32 rows)
  const int dmt = idx >> 5;       // decoder M-split (8 rows)

  const int bflag = idx * 32;     // 128B stride: no line sharing
  const int pf0 = (lane * 4 + 0) * 32;
  const int pf1 = (lane * 4 + 1) * 32;
  const int pf2 = (lane * 4 + 2) * 32;
  const int pf3 = (lane * 4 + 3) * 32;

  // A-stage buffer [kh][row][520] (padded rows), UNIONED with zred (disjoint
  // lifetimes, separated by RAWBARs).
  __shared__ __align__(16) char ubuf[2 * 32 * 520 * 2];
  f16 (*const As)[32][520] = (f16(*)[32][520])ubuf;
  float (*const zred)[32][17] = (float(*)[32][17])ubuf;
  __shared__ float bias_enc_lds[4 * 4 * 16];    // [L][g][ci]
  __shared__ float bias_dec_lds[16 * 4 * 16];   // [L*4+E][g][ci]

  const long wslice = ((long)(nt * 4 + g) * 2 + kh) * 8192 + lane * 8;
  const int HSz = BS * SH;
  const f16* const state0 = h_enc + (1 * 4 + 3) * HSz;

  // stage biases into LDS once
  for (int i = tid; i < 256; i += 512) {
    int L = i >> 6, gg = (i >> 4) & 3, ci = i & 15;
    bias_enc_lds[i] = enc_b[(L * 4 + eslot) * 2048 + gg * 512 + n0 + ci];
  }
  for (int i = tid; i < 1024; i += 512) {
    int cell = i >> 6, gg = (i >> 4) & 3, ci = i & 15;
    bias_dec_lds[i] = dec_b[cell * 2048 + gg * 512 + n0 + ci];
  }

  f16x8 B[16];
  {  // preload first encoder cell (L=0, e=eslot)
    const f16* w = wt_enc + ((long)eslot << 21) + wslice;
#pragma unroll
    for (int kk = 0; kk < 16; ++kk) B[kk] = *(const f16x8*)(w + kk * 512);
  }
  __syncthreads();  // biases staged

  float ce = 0.f;
  float cd0 = 0.f, cd1 = 0.f, cd2 = 0.f, cd3 = 0.f;

  // -------- encoder: anti-diagonal wavefront, diagonals 0..1026 --------
  for (int d = 0;; d += 2) {
    ENC_BODY(d, 0, d + 1);
    if (d == 1026) break;
    ENC_BODY(d + 1, 1, d + 2);
  }

  // -------- decoder: fully serial, 4096 cells, unrolled x4 --------
  for (int vv = 0; vv < 1024; ++vv) {
    const int L = vv & 3, par = vv & 1;
    DEC_BODY(0, cd0, ESTEPS + vv * 4 + 1);
    DEC_BODY(1, cd1, ESTEPS + vv * 4 + 2);
    DEC_BODY(2, cd2, ESTEPS + vv * 4 + 3);
    DEC_BODY(3, cd3, ESTEPS + vv * 4 + 4);
  }
}

// out[m][n] = sigmoid( ys[m][:] @ fint[n][:] + fin_b[n] )
__global__ __launch_bounds__(256) void final_gemm(const f16* __restrict__ ys,
                                                  const f16* __restrict__ fint,
                                                  const float* __restrict__ finb,
                                                  float* __restrict__ out) {
  const int lane = threadIdx.x & 63;
  const int w = threadIdx.x >> 6;
  const int col = lane & 15;
  const int kg = lane >> 4;
  const long m0 = (long)blockIdx.y * 64;
  const int n0 = (blockIdx.x * 4 + w) * 16;

  f32x4 acc[4];
#pragma unroll
  for (int mi = 0; mi < 4; ++mi) acc[mi] = 0.f;

#pragma unroll 2
  for (int kk = 0; kk < 16; ++kk) {
    f16x8 b = *(const f16x8*)(fint + (long)(n0 + col) * 512 + kk * 32 + kg * 8);
#pragma unroll
    for (int mi = 0; mi < 4; ++mi) {
      f16x8 a = *(const f16x8*)(ys + (m0 + mi * 16 + col) * 512 + kk * 32 + kg * 8);
      acc[mi] = __builtin_amdgcn_mfma_f32_16x16x32_f16(a, b, acc[mi], 0, 0, 0);
    }
  }
  const int n = n0 + col;
  const float bn = finb[n];
#pragma unroll
  for (int mi = 0; mi < 4; ++mi)
#pragma unroll
    for (int r = 0; r < 4; ++r)
      out[(m0 + mi * 16 + kg * 4 + r) * 512 + n] = sigmoidf_(acc[mi][r] + bn);
}

extern "C" void kernel_launch(void* const* d_in, const int* in_sizes, int n_in,
                              void* d_out, int out_size, void* d_ws, size_t ws_size,
                              hipStream_t stream) {
  const float* x      = (const float*)d_in[0];
  const float* enc_W  = (const float*)d_in[2];
  const float* enc_V  = (const float*)d_in[3];
  const float* enc_b  = (const float*)d_in[4];
  const float* enc_h0 = (const float*)d_in[5];
  const float* enc_c0 = (const float*)d_in[6];
  const float* dec_W  = (const float*)d_in[7];
  const float* dec_V  = (const float*)d_in[8];
  const float* dec_b  = (const float*)d_in[9];
  const float* dec_h0 = (const float*)d_in[10];
  const float* dec_c0 = (const float*)d_in[11];
  const float* fin_W  = (const float*)d_in[12];
  const float* fin_b  = (const float*)d_in[13];
  float* out = (float*)d_out;

  // workspace layout
  f16* wt_enc = (f16*)d_ws;                                   // 16*2048*1024
  f16* wt_dec = wt_enc + (long)16 * 2048 * 1024;              // 16*2048*1024
  f16* xt     = wt_dec + (long)16 * 2048 * 1024;              // 256*64*512
  f16* fint   = xt + (long)SL * BS * SI;                      // 512*512
  f16* ys     = fint + (long)SH * SI;                         // 64*1024*512
  f16* h_enc  = ys + (long)BS * (FL * 4) * SH;                // 2*4*64*512
  f16* h_dec  = h_enc + (long)2 * 4 * BS * SH;                // 2*4*64*512
  float* c_unused = (float*)(h_dec + (long)2 * 4 * BS * SH);  // reserved
  int* bar = (int*)(c_unused + (long)8 * BS * SH);            // 256 flags x 128B

  hipMemsetAsync(bar, 0, 65536, stream);

  conv_w<<<131072, 256, 0, stream>>>(enc_W, enc_V, wt_enc);
  conv_w<<<131072, 256, 0, stream>>>(dec_W, dec_V, wt_dec);
  conv_x<<<32768, 256, 0, stream>>>(x, xt);
  conv_fin<<<1024, 256, 0, stream>>>(fin_W, fint);
  init_state<<<512, 256, 0, stream>>>(enc_h0, dec_h0, h_enc, h_dec);

  lstm_persist<<<NBLK, 512, 0, stream>>>(xt, wt_enc, wt_dec, enc_b, dec_b,
                                         enc_c0, dec_c0, h_enc, h_dec, ys, bar);

  dim3 fg(8, 1024);
  final_gemm<<<fg, 256, 0, stream>>>(ys, fint, fin_b, out);
}

// Round 10
// 20500.087 us; speedup vs baseline: 2.4581x; 1.2052x over previous
//
#include <hip/hip_runtime.h>

typedef _Float16 f16;
typedef _Float16 f16x8 __attribute__((ext_vector_type(8)));
typedef float f32x4 __attribute__((ext_vector_type(4)));

#define BS 64
#define SL 256
#define FL 256
#define SI 512
#define SH 512
#define NBLK 256
#define TFULL 1028   // full-barrier target between encoder and decoder phases

__device__ __forceinline__ float sigmoidf_(float x) { return 1.f / (1.f + __expf(-x)); }
__device__ __forceinline__ float tanhf_(float x) { float e = __expf(2.f * x); return 1.f - 2.f / (e + 1.f); }

// Coherent 16B load: bypass L1+L2, read from the device coherence point (L3).
__device__ __forceinline__ f16x8 ldg_cohere(const f16* p) {
  f16x8 r;
  asm volatile("global_load_dwordx4 %0, %1, off sc0 sc1"
               : "=v"(r) : "v"(p) : "memory");
  return r;
}

// Weights packed in MFMA-fragment order (unchanged):
// widx = (((((cell*32+nt)*4+g)*2+kh)*16+kk)*64 + lane)*8 + j
// n = g*512 + nt*16 + (lane&15), k = kh*512 + kk*32 + (lane>>4)*8 + j
__global__ void conv_w(const float* __restrict__ W, const float* __restrict__ V,
                       f16* __restrict__ out) {
  long idx = (long)blockIdx.x * blockDim.x + threadIdx.x;  // total 2^25
  int j    = (int)(idx & 7);
  int lane = (int)((idx >> 3) & 63);
  int kk   = (int)((idx >> 9) & 15);
  int kh   = (int)((idx >> 13) & 1);
  int g    = (int)((idx >> 14) & 3);
  int nt   = (int)((idx >> 16) & 31);
  long cell = idx >> 21;
  int n = g * 512 + nt * 16 + (lane & 15);
  int k = kh * 512 + kk * 32 + (lane >> 4) * 8 + j;
  float v = (k < 512) ? W[(cell * 512 + k) * 2048 + n]
                      : V[(cell * 512 + (k - 512)) * 2048 + n];
  out[idx] = (f16)v;
}

__global__ void conv_x(const float* __restrict__ x, f16* __restrict__ xt) {
  long idx = (long)blockIdx.x * blockDim.x + threadIdx.x;  // 256*64*512
  int i = (int)(idx & 511);
  int b = (int)((idx >> 9) & 63);
  int t = (int)(idx >> 15);
  xt[idx] = (f16)x[((long)b * SL + t) * SI + i];
}

__global__ void conv_fin(const float* __restrict__ finW, f16* __restrict__ fint) {
  long idx = (long)blockIdx.x * blockDim.x + threadIdx.x;  // 512*512
  int k = (int)(idx & 511);
  int n = (int)(idx >> 9);
  fint[idx] = (f16)finW[(long)k * SI + n];
}

// h_enc both parities = enc_h0 ; h_dec parity-1 slabs = dec_h0
__global__ void init_state(const float* __restrict__ h0e, const float* __restrict__ h0d,
                           f16* __restrict__ h_enc, f16* __restrict__ h_dec) {
  long idx = (long)blockIdx.x * blockDim.x + threadIdx.x;  // 4*64*512 = 131072
  f16 he = (f16)h0e[idx];
  h_enc[idx] = he;
  h_enc[idx + 131072] = he;
  h_dec[idx + 131072] = (f16)h0d[idx];
}

__device__ __forceinline__ void store_h_agent(f16* p, float v) {
  f16 h = (f16)v;
  __hip_atomic_store((unsigned short*)p, __builtin_bit_cast(unsigned short, h),
                     __ATOMIC_RELAXED, __HIP_MEMORY_SCOPE_AGENT);
}

// XOR-swizzled LDS byte offset within a chunk: row stride 1024B, T2-style
// (row&7)<<4 spread so both staging writes and fragment reads are <=2-way.
#define SWZ(ROW, BOFF) (((ROW) << 10) + ((BOFF) ^ ((((ROW) & 7)) << 4)))

#define VMCNT0() do {                                                             \
    asm volatile("s_waitcnt vmcnt(0)" ::: "memory");                              \
    __builtin_amdgcn_sched_barrier(0);                                            \
  } while (0)

// Block barrier for LDS visibility only: lgkmcnt drain, vmcnt stays in flight.
#define RAWBAR() do {                                                             \
    asm volatile("s_waitcnt lgkmcnt(0)" ::: "memory");                            \
    __builtin_amdgcn_sched_barrier(0);                                            \
    __builtin_amdgcn_s_barrier();                                                 \
    __builtin_amdgcn_sched_barrier(0);                                            \
  } while (0)

// Ordered arrive: h/ys stores (older) acked at coherence point by vmcnt(16);
// the 16 weight-prefetch loads (newer) keep flying across the barrier.
#define WAVE_ORDER() do {                                                          \
    asm volatile("s_waitcnt vmcnt(16)" ::: "memory");                              \
    __builtin_amdgcn_sched_barrier(0);                                             \
  } while (0)

// Group barrier, encoder scope (128 blocks sharing emt): 2 flags per lane.
#define END_STEP_ENC(TARGET) do {                                                  \
    __builtin_amdgcn_s_barrier();                                                  \
    asm volatile("" ::: "memory");                                                 \
    if (tid == 0)                                                                  \
      __hip_atomic_store(&bar[bflag], (TARGET), __ATOMIC_RELAXED,                  \
                         __HIP_MEMORY_SCOPE_AGENT);                                \
    if (wid == 0) {                                                                \
      for (;;) {                                                                   \
        int a0 = __hip_atomic_load(&bar[pe0], __ATOMIC_RELAXED,                    \
                                   __HIP_MEMORY_SCOPE_AGENT);                      \
        int a1 = __hip_atomic_load(&bar[pe1], __ATOMIC_RELAXED,                    \
                                   __HIP_MEMORY_SCOPE_AGENT);                      \
        if (a0 >= (TARGET) && a1 >= (TARGET)) break;                               \
        __builtin_amdgcn_s_sleep(1);                                               \
      }                                                                            \
    }                                                                              \
    __builtin_amdgcn_s_barrier();                                                  \
    asm volatile("" ::: "memory");                                                 \
    __builtin_amdgcn_sched_barrier(0);                                             \
  } while (0)

// Group barrier, decoder scope (32 blocks sharing dmt): 1 flag per lane.
#define END_STEP_DEC(TARGET) do {                                                  \
    __builtin_amdgcn_s_barrier();                                                  \
    asm volatile("" ::: "memory");                                                 \
    if (tid == 0)                                                                  \
      __hip_atomic_store(&bar[bflag], (TARGET), __ATOMIC_RELAXED,                  \
                         __HIP_MEMORY_SCOPE_AGENT);                                \
    if (wid == 0) {                                                                \
      while (__hip_atomic_load(&bar[pd], __ATOMIC_RELAXED,                         \
                               __HIP_MEMORY_SCOPE_AGENT) < (TARGET))               \
        __builtin_amdgcn_s_sleep(1);                                               \
    }                                                                              \
    __builtin_amdgcn_s_barrier();                                                  \
    asm volatile("" ::: "memory");                                                 \
    __builtin_amdgcn_sched_barrier(0);                                             \
  } while (0)

// Full 256-block barrier (encoder -> decoder transition only).
#define END_STEP_FULL(TARGET) do {                                                 \
    __builtin_amdgcn_s_barrier();                                                  \
    asm volatile("" ::: "memory");                                                 \
    if (tid == 0)                                                                  \
      __hip_atomic_store(&bar[bflag], (TARGET), __ATOMIC_RELAXED,                  \
                         __HIP_MEMORY_SCOPE_AGENT);                                \
    if (wid == 0) {                                                                \
      for (;;) {                                                                   \
        int a0 = __hip_atomic_load(&bar[pf0], __ATOMIC_RELAXED,                    \
                                   __HIP_MEMORY_SCOPE_AGENT);                      \
        int a1 = __hip_atomic_load(&bar[pf1], __ATOMIC_RELAXED,                    \
                                   __HIP_MEMORY_SCOPE_AGENT);                      \
        int a2 = __hip_atomic_load(&bar[pf2], __ATOMIC_RELAXED,                    \
                                   __HIP_MEMORY_SCOPE_AGENT);                      \
        int a3 = __hip_atomic_load(&bar[pf3], __ATOMIC_RELAXED,                    \
                                   __HIP_MEMORY_SCOPE_AGENT);                      \
        if (a0 >= (TARGET) && a1 >= (TARGET) && a2 >= (TARGET) && a3 >= (TARGET))  \
          break;                                                                   \
        __builtin_amdgcn_s_sleep(2);                                               \
      }                                                                            \
    }                                                                              \
    __builtin_amdgcn_s_barrier();                                                  \
    asm volatile("" ::: "memory");                                                 \
    __builtin_amdgcn_sched_barrier(0);                                             \
  } while (0)

// Encoder body. Stage 64KB (inp+hin, 32 rows each) into swizzled LDS.
#define ENC_BODY(DD, P, TARGET) do {                                               \
    const int v = (DD) - eslot;                                                    \
    if (v >= 0 && v < 1024) {                                                      \
      const int L = v & 3, t = v >> 2;                                             \
      const f16* inp = (eslot == 0) ? (xt + (long)t * HSz)                         \
                                    : (h_enc + ((P)*4 + (eslot - 1)) * HSz);       \
      const f16* hin = h_enc + ((P)*4 + eslot) * HSz;                              \
      f16* hout = h_enc + ((1 - (P))*4 + eslot) * HSz;                             \
      { /* stage: slot s -> row=s>>6 (0..31), c16=s&63; wave = 1 row, 1KB */       \
        const f16* c0p = inp + emt * 16384;                                        \
        const f16* c1p = hin + emt * 16384;                                        \
        f16x8 tr[8];                                                               \
        _Pragma("unroll")                                                          \
        for (int k2 = 0; k2 < 4; ++k2) {                                           \
          const int s = tid + k2 * 512, row = s >> 6, c16 = s & 63;                \
          tr[k2]     = ldg_cohere(c0p + row * 512 + c16 * 8);                      \
          tr[k2 + 4] = ldg_cohere(c1p + row * 512 + c16 * 8);                      \
        }                                                                          \
        VMCNT0();                                                                  \
        _Pragma("unroll")                                                          \
        for (int k2 = 0; k2 < 4; ++k2) {                                           \
          const int s = tid + k2 * 512, row = s >> 6, c16 = s & 63;                \
          *(f16x8*)(AsBuf + SWZ(row, c16 * 16)) = tr[k2];                          \
          *(f16x8*)(AsBuf + 32768 + SWZ(row, c16 * 16)) = tr[k2 + 4];              \
        }                                                                          \
      }                                                                            \
      RAWBAR();                                                                    \
      f32x4 acc0 = 0.f, acc1 = 0.f;                                                \
      _Pragma("unroll")                                                            \
      for (int kk = 0; kk < 16; ++kk) {                                            \
        f16x8 a0 = *(const f16x8*)(AsBuf + kh * 32768 +                            \
                                   SWZ(col, kk * 64 + kg * 16));                   \
        f16x8 a1 = *(const f16x8*)(AsBuf + kh * 32768 +                            \
                                   SWZ(col + 16, kk * 64 + kg * 16));              \
        acc0 = __builtin_amdgcn_mfma_f32_16x16x32_f16(a0, B[kk], acc0, 0,0,0);     \
        acc1 = __builtin_amdgcn_mfma_f32_16x16x32_f16(a1, B[kk], acc1, 0,0,0);     \
      }                                                                            \
      _Pragma("unroll")                                                            \
      for (int r = 0; r < 4; ++r) {                                                \
        zred[wid][kg*4 + r][col] = acc0[r];                                        \
        zred[wid][16 + kg*4 + r][col] = acc1[r];                                   \
      }                                                                            \
      RAWBAR();                                                                    \
      {                                                                            \
        const int row = tid >> 4, ci = tid & 15, n = n0 + ci;                      \
        const float* bl = bias_enc_lds + L * 64 + ci;                              \
        float zf = bl[0]  + zred[0][row][ci] + zred[4][row][ci];                   \
        float zi = bl[16] + zred[1][row][ci] + zred[5][row][ci];                   \
        float zg = bl[32] + zred[2][row][ci] + zred[6][row][ci];                   \
        float zo = bl[48] + zred[3][row][ci] + zred[7][row][ci];                   \
        float f_ = sigmoidf_(zf), i_ = sigmoidf_(zi);                              \
        float g_ = tanhf_(zg),   o_ = sigmoidf_(zo);                               \
        const int grow = emt * 32 + row;                                           \
        float cin = (v == 0) ? enc_c0[(long)eslot * HSz + grow * SH + n] : ce;     \
        float cc = f_ * cin + i_ * g_;                                             \
        ce = cc;                                                                   \
        store_h_agent(hout + grow * SH + n, o_ * tanhf_(cc));                      \
      }                                                                            \
      const f16* wn = (v + 1 < 1024)                                               \
          ? wt_enc + ((long)(((v + 1) & 3) * 4 + eslot) << 21) + wslice            \
          : wt_dec + wslice;                                                       \
      asm volatile("" ::: "memory");                                               \
      _Pragma("unroll")                                                            \
      for (int kk = 0; kk < 16; ++kk) B[kk] = *(const f16x8*)(wn + kk * 512);      \
      WAVE_ORDER();                                                                \
    }                                                                              \
    END_STEP_ENC(TARGET);                                                          \
  } while (0)

// Decoder body. Stage 16KB (inp+hin, 8 rows each) into swizzled LDS.
#define DEC_BODY(E, CD, TARGET) do {                                               \
    const f16* inp;                                                                \
    if ((E) == 0)                                                                  \
      inp = (vv == 0) ? state0 : h_dec + ((par ^ 1) * 4 + 3) * HSz;                \
    else                                                                           \
      inp = h_dec + (par * 4 + (E) - 1) * HSz;                                     \
    const f16* hin = h_dec + ((par ^ 1) * 4 + (E)) * HSz;                          \
    f16* hout = h_dec + (par * 4 + (E)) * HSz;                                     \
    {                                                                              \
      const int drow = tid >> 6, dc16 = tid & 63;                                  \
      f16x8 t0 = ldg_cohere(inp + dmt * 4096 + drow * 512 + dc16 * 8);             \
      f16x8 t1 = ldg_cohere(hin + dmt * 4096 + drow * 512 + dc16 * 8);             \
      VMCNT0();                                                                    \
      *(f16x8*)(AsBuf + SWZ(drow, dc16 * 16)) = t0;                                \
      *(f16x8*)(AsBuf + 8192 + SWZ(drow, dc16 * 16)) = t1;                         \
    }                                                                              \
    RAWBAR();                                                                      \
    f32x4 acc = 0.f;                                                               \
    _Pragma("unroll")                                                              \
    for (int kk = 0; kk < 16; ++kk) {                                              \
      f16x8 a = *(const f16x8*)(AsBuf + kh * 8192 +                                \
                                SWZ(col & 7, kk * 64 + kg * 16));                  \
      acc = __builtin_amdgcn_mfma_f32_16x16x32_f16(a, B[kk], acc, 0,0,0);          \
    }                                                                              \
    if (kg < 2) {                                                                  \
      _Pragma("unroll")                                                            \
      for (int r = 0; r < 4; ++r) zred[wid][kg*4 + r][col] = acc[r];               \
    }                                                                              \
    RAWBAR();                                                                      \
    if (tid < 128) {                                                               \
      const int row = tid >> 4, ci = tid & 15, n = n0 + ci;                        \
      const float* bl = bias_dec_lds + (L * 4 + (E)) * 64 + ci;                    \
      float zf = bl[0]  + zred[0][row][ci] + zred[4][row][ci];                     \
      float zi = bl[16] + zred[1][row][ci] + zred[5][row][ci];                     \
      float zg = bl[32] + zred[2][row][ci] + zred[6][row][ci];                     \
      float zo = bl[48] + zred[3][row][ci] + zred[7][row][ci];                     \
      float f_ = sigmoidf_(zf), i_ = sigmoidf_(zi);                                \
      float g_ = tanhf_(zg),   o_ = sigmoidf_(zo);                                 \
      const int grow = dmt * 8 + row;                                              \
      float cin = (vv == 0) ? dec_c0[(long)(E) * HSz + grow * SH + n] : CD;        \
      float cc = f_ * cin + i_ * g_;                                               \
      CD = cc;                                                                     \
      float hv = o_ * tanhf_(cc);                                                  \
      store_h_agent(hout + grow * SH + n, hv);                                     \
      if ((E) == 3) ys[((long)grow * 1024 + vv) * SH + n] = (f16)hv;               \
    }                                                                              \
    {                                                                              \
      const int Lp = ((E) < 3) ? L : ((vv + 1) & 3);                               \
      const int Ep = ((E) + 1) & 3;                                                \
      const f16* wn = wt_dec + ((long)(Lp * 4 + Ep) << 21) + wslice;               \
      asm volatile("" ::: "memory");                                               \
      _Pragma("unroll")                                                            \
      for (int kk = 0; kk < 16; ++kk) B[kk] = *(const f16x8*)(wn + kk * 512);      \
      WAVE_ORDER();                                                                \
    }                                                                              \
    END_STEP_DEC(TARGET);                                                          \
  } while (0)

__global__ __launch_bounds__(512, 2) void lstm_persist(
    const f16* __restrict__ xt,
    const f16* __restrict__ wt_enc, const f16* __restrict__ wt_dec,
    const float* __restrict__ enc_b, const float* __restrict__ dec_b,
    const float* __restrict__ enc_c0, const float* __restrict__ dec_c0,
    f16* __restrict__ h_enc, f16* __restrict__ h_dec,
    f16* __restrict__ ys, int* __restrict__ bar) {
  const int tid = threadIdx.x;
  const int lane = tid & 63;
  const int wid = tid >> 6;   // 0..7
  const int g = wid & 3;      // gate
  const int kh = wid >> 2;    // K-half
  const int col = lane & 15;
  const int kg = lane >> 4;
  const int idx = blockIdx.x;
  const int nt = idx & 31;        // idx%8 == nt%8 -> weight-sharing siblings co-XCD
  const int n0 = nt << 4;
  const int eslot = idx >> 6;     // encoder role: 4 groups of 64 blocks
  const int emt = (idx >> 5) & 1; // encoder M-split (32 rows) = encoder sync group
  const int dmt = idx >> 5;       // decoder M-split (8 rows)  = decoder sync group

  const int bflag = idx * 32;     // 128B flag stride
  // encoder group poll: 128 members (bit5 == emt), 2 flags per lane
  const int pe0 = ((((lane) >> 5) << 6) | (emt << 5) | (lane & 31)) * 32;
  const int pe1 = (((((lane + 64)) >> 5) << 6) | (emt << 5) | ((lane + 64) & 31)) * 32;
  // decoder group poll: 32 members (same dmt), 1 flag per lane (dup lanes 32-63)
  const int pd = (dmt * 32 + (lane & 31)) * 32;
  // full barrier poll
  const int pf0 = (lane * 4 + 0) * 32;
  const int pf1 = (lane * 4 + 1) * 32;
  const int pf2 = (lane * 4 + 2) * 32;
  const int pf3 = (lane * 4 + 3) * 32;

  __shared__ __align__(16) char AsBuf[65536];   // swizzled A-stage (enc 64KB / dec 16KB)
  __shared__ float zred[8][32][17];
  __shared__ float bias_enc_lds[4 * 4 * 16];    // [L][g][ci]
  __shared__ float bias_dec_lds[16 * 4 * 16];   // [L*4+E][g][ci]

  const long wslice = ((long)(nt * 4 + g) * 2 + kh) * 8192 + lane * 8;
  const int HSz = BS * SH;
  const f16* const state0 = h_enc + (1 * 4 + 3) * HSz;

  // stage biases into LDS once
  for (int i = tid; i < 256; i += 512) {
    int L = i >> 6, gg = (i >> 4) & 3, ci = i & 15;
    bias_enc_lds[i] = enc_b[(L * 4 + eslot) * 2048 + gg * 512 + n0 + ci];
  }
  for (int i = tid; i < 1024; i += 512) {
    int cell = i >> 6, gg = (i >> 4) & 3, ci = i & 15;
    bias_dec_lds[i] = dec_b[cell * 2048 + gg * 512 + n0 + ci];
  }

  f16x8 B[16];
  {  // preload first encoder cell (L=0, e=eslot)
    const f16* w = wt_enc + ((long)eslot << 21) + wslice;
#pragma unroll
    for (int kk = 0; kk < 16; ++kk) B[kk] = *(const f16x8*)(w + kk * 512);
  }
  __syncthreads();  // biases staged

  float ce = 0.f;
  float cd0 = 0.f, cd1 = 0.f, cd2 = 0.f, cd3 = 0.f;

  // -------- encoder: anti-diagonal wavefront, diagonals 0..1026 --------
  // (2 independent sync groups of 128 blocks, split by emt row ownership)
  for (int d = 0;; d += 2) {
    ENC_BODY(d, 0, d + 1);
    if (d == 1026) break;
    ENC_BODY(d + 1, 1, d + 2);
  }

  // -------- full barrier: state0 crosses encoder groups --------
  END_STEP_FULL(TFULL);

  // -------- decoder: 8 independent 32-block chains (dmt row ownership) --------
  for (int vv = 0; vv < 1024; ++vv) {
    const int L = vv & 3, par = vv & 1;
    DEC_BODY(0, cd0, TFULL + vv * 4 + 1);
    DEC_BODY(1, cd1, TFULL + vv * 4 + 2);
    DEC_BODY(2, cd2, TFULL + vv * 4 + 3);
    DEC_BODY(3, cd3, TFULL + vv * 4 + 4);
  }
}

// out[m][n] = sigmoid( ys[m][:] @ fint[n][:] + fin_b[n] )
__global__ __launch_bounds__(256) void final_gemm(const f16* __restrict__ ys,
                                                  const f16* __restrict__ fint,
                                                  const float* __restrict__ finb,
                                                  float* __restrict__ out) {
  const int lane = threadIdx.x & 63;
  const int w = threadIdx.x >> 6;
  const int col = lane & 15;
  const int kg = lane >> 4;
  const long m0 = (long)blockIdx.y * 64;
  const int n0 = (blockIdx.x * 4 + w) * 16;

  f32x4 acc[4];
#pragma unroll
  for (int mi = 0; mi < 4; ++mi) acc[mi] = 0.f;

#pragma unroll 2
  for (int kk = 0; kk < 16; ++kk) {
    f16x8 b = *(const f16x8*)(fint + (long)(n0 + col) * 512 + kk * 32 + kg * 8);
#pragma unroll
    for (int mi = 0; mi < 4; ++mi) {
      f16x8 a = *(const f16x8*)(ys + (m0 + mi * 16 + col) * 512 + kk * 32 + kg * 8);
      acc[mi] = __builtin_amdgcn_mfma_f32_16x16x32_f16(a, b, acc[mi], 0, 0, 0);
    }
  }
  const int n = n0 + col;
  const float bn = finb[n];
#pragma unroll
  for (int mi = 0; mi < 4; ++mi)
#pragma unroll
    for (int r = 0; r < 4; ++r)
      out[(m0 + mi * 16 + kg * 4 + r) * 512 + n] = sigmoidf_(acc[mi][r] + bn);
}

extern "C" void kernel_launch(void* const* d_in, const int* in_sizes, int n_in,
                              void* d_out, int out_size, void* d_ws, size_t ws_size,
                              hipStream_t stream) {
  const float* x      = (const float*)d_in[0];
  const float* enc_W  = (const float*)d_in[2];
  const float* enc_V  = (const float*)d_in[3];
  const float* enc_b  = (const float*)d_in[4];
  const float* enc_h0 = (const float*)d_in[5];
  const float* enc_c0 = (const float*)d_in[6];
  const float* dec_W  = (const float*)d_in[7];
  const float* dec_V  = (const float*)d_in[8];
  const float* dec_b  = (const float*)d_in[9];
  const float* dec_h0 = (const float*)d_in[10];
  const float* dec_c0 = (const float*)d_in[11];
  const float* fin_W  = (const float*)d_in[12];
  const float* fin_b  = (const float*)d_in[13];
  float* out = (float*)d_out;

  // workspace layout
  f16* wt_enc = (f16*)d_ws;                                   // 16*2048*1024
  f16* wt_dec = wt_enc + (long)16 * 2048 * 1024;              // 16*2048*1024
  f16* xt     = wt_dec + (long)16 * 2048 * 1024;              // 256*64*512
  f16* fint   = xt + (long)SL * BS * SI;                      // 512*512
  f16* ys     = fint + (long)SH * SI;                         // 64*1024*512
  f16* h_enc  = ys + (long)BS * (FL * 4) * SH;                // 2*4*64*512
  f16* h_dec  = h_enc + (long)2 * 4 * BS * SH;                // 2*4*64*512
  float* c_unused = (float*)(h_dec + (long)2 * 4 * BS * SH);  // reserved
  int* bar = (int*)(c_unused + (long)8 * BS * SH);            // 256 flags x 128B

  hipMemsetAsync(bar, 0, 65536, stream);

  conv_w<<<131072, 256, 0, stream>>>(enc_W, enc_V, wt_enc);
  conv_w<<<131072, 256, 0, stream>>>(dec_W, dec_V, wt_dec);
  conv_x<<<32768, 256, 0, stream>>>(x, xt);
  conv_fin<<<1024, 256, 0, stream>>>(fin_W, fint);
  init_state<<<512, 256, 0, stream>>>(enc_h0, dec_h0, h_enc, h_dec);

  lstm_persist<<<NBLK, 512, 0, stream>>>(xt, wt_enc, wt_dec, enc_b, dec_b,
                                         enc_c0, dec_c0, h_enc, h_dec, ys, bar);

  dim3 fg(8, 1024);
  final_gemm<<<fg, 256, 0, stream>>>(ys, fint, fin_b, out);
}